// Round 12
// baseline (197.715 us; speedup 1.0000x reference)
//
#include <hip/hip_runtime.h>
#include <math.h>

#define BATCH     128
#define N_NODES   32768
#define N_CHILD   65536
#define NNZ_TOTAL 1048576
#define LOG2E     1.44269504f

typedef __attribute__((ext_vector_type(2))) float fx2;

// ---------------------------------------------------------------------------
// Kernel A: fp8 exp table, per-column power-of-2 scale, register-resident.
// ---------------------------------------------------------------------------
__global__ __launch_bounds__(256) void exp8_kernel(
    const float* __restrict__ child_ll, unsigned char* __restrict__ ex8,
    float* __restrict__ winv) {
    const int c0 = blockIdx.x * 64;
    const int t  = threadIdx.x;
    const int cl = t & 63;
    const int q  = t >> 6;                 // batch quarter [q*32, q*32+32)

    float v[32];
    float m = -3.4e38f;
    const float* bp = child_ll + (size_t)(q * 32) * N_CHILD + c0 + cl;
#pragma unroll
    for (int j = 0; j < 32; ++j) {
        v[j] = bp[(size_t)j * N_CHILD];
        m = fmaxf(m, v[j]);
    }

    __shared__ float smx[4][64];
    __shared__ float skf[64];
    smx[q][cl] = m;
    __syncthreads();
    if (t < 64) {
        const float mm = fmaxf(fmaxf(smx[0][t], smx[1][t]),
                               fmaxf(smx[2][t], smx[3][t]));
        const int ks = 7 - (int)floorf(mm * LOG2E);   // colmax*2^ks in [128,256)
        skf[t] = (float)ks;
        winv[c0 + t] = exp2f((float)(-ks));
    }
    __syncthreads();
    const float kf = skf[cl];

    unsigned ow[8];
#pragma unroll
    for (int p = 0; p < 8; ++p) {
        const float a0 = exp2f(fmaf(v[4 * p + 0], LOG2E, kf));
        const float a1 = exp2f(fmaf(v[4 * p + 1], LOG2E, kf));
        const float a2 = exp2f(fmaf(v[4 * p + 2], LOG2E, kf));
        const float a3 = exp2f(fmaf(v[4 * p + 3], LOG2E, kf));
        unsigned u = 0;
        u = __builtin_amdgcn_cvt_pk_fp8_f32(a0, a1, u, false);
        u = __builtin_amdgcn_cvt_pk_fp8_f32(a2, a3, u, true);
        ow[p] = u;
    }

    __shared__ unsigned char sby[64 * 144];
    *(uint4*)&sby[cl * 144 + q * 32]      = *(uint4*)&ow[0];
    *(uint4*)&sby[cl * 144 + q * 32 + 16] = *(uint4*)&ow[4];
    __syncthreads();

    const int sub = t & 7, cc = t >> 3;
#pragma unroll
    for (int p = 0; p < 2; ++p) {
        const int c = cc + p * 32;
        *(uint4*)&ex8[(size_t)(c0 + c) * 128 + sub * 16] =
            *(const uint4*)&sby[c * 144 + sub * 16];
    }
}

// ---------------------------------------------------------------------------
// Kernel B: wfold[i] = exp(log_w[i]) * winv[cols[i]]  +  row_start via
// sorted-COO scan (no binary search). 4 nnz per thread, fully coalesced.
// ---------------------------------------------------------------------------
__global__ __launch_bounds__(256) void fold_scan_kernel(
    const float* __restrict__ log_w, const int* __restrict__ cols,
    const float* __restrict__ winv, const int* __restrict__ rows,
    float* __restrict__ wfold, int* __restrict__ row_start) {
    const int i = (blockIdx.x * 256 + threadIdx.x) * 4;
    const float4 lw = *(const float4*)&log_w[i];
    const int4   cc = *(const int4*)&cols[i];
    float4 o;
    o.x = expf(lw.x) * winv[cc.x];
    o.y = expf(lw.y) * winv[cc.y];
    o.z = expf(lw.z) * winv[cc.z];
    o.w = expf(lw.w) * winv[cc.w];
    *(float4*)&wfold[i] = o;

    const int4 rv = *(const int4*)&rows[i];
    const int rj[4] = {rv.x, rv.y, rv.z, rv.w};
    int prev = (i == 0) ? -1 : rows[i - 1];
#pragma unroll
    for (int j = 0; j < 4; ++j) {
        const int cur = rj[j];
        if (cur != prev)
            for (int q = prev + 1; q <= cur; ++q) row_start[q] = i + j;
        prev = cur;
    }
    if (i + 3 == NNZ_TOTAL - 1)
        for (int q = rj[3] + 1; q <= N_NODES; ++q) row_start[q] = NNZ_TOTAL;
}

// ---------------------------------------------------------------------------
// Kernel C: logzv[r] = log(sum exp(log_w[row segment])). 16 lanes/row.
// ---------------------------------------------------------------------------
__global__ __launch_bounds__(256) void logz_kernel(
    const float* __restrict__ log_w, const int* __restrict__ row_start,
    float* __restrict__ logzv) {
    const int t = threadIdx.x;
    const int g = t >> 4, j = t & 15;
    const int r = blockIdx.x * 16 + g;
    const int s = row_start[r], e = row_start[r + 1];
    float sum = 0.f;
    for (int i = s + j; i < e; i += 16) sum += expf(log_w[i]);
    sum += __shfl_xor(sum, 1, 64);
    sum += __shfl_xor(sum, 2, 64);
    sum += __shfl_xor(sum, 4, 64);
    sum += __shfl_xor(sum, 8, 64);
    if (j == 0) logzv[r] = logf(sum);
}

// ---------------------------------------------------------------------------
// Kernel D: per-row sum, one wave per row (R11 schedule), with residency
// cap raised to 8 blocks/CU (launch_bounds min-waves/EU = 8; VGPR 56 <= 64
// budget) to double outstanding gathers per CU.
// ---------------------------------------------------------------------------
__global__ __launch_bounds__(256, 8) void sum_rows_kernel(
    const unsigned char* __restrict__ ex8, const float* __restrict__ wfold,
    const int* __restrict__ cols, const int* __restrict__ row_start,
    const float* __restrict__ logzv, float* __restrict__ out) {
    const int wave = threadIdx.x >> 6;   // 0..3
    const int lane = threadIdx.x & 63;
    const int bid  = blockIdx.x;         // grid = 8192
    const int rb   = (bid & 7) * (N_NODES / 4 / 8) + (bid >> 3);
    const int r    = rb * 4 + wave;

    const int start = row_start[r];
    const int end   = row_start[r + 1];
    const float lz  = logzv[r];                    // issued early, used last
    const int  slot = lane >> 3;                   // nnz slot within granule
    const unsigned sub = (unsigned)lane & 7u;      // 16B chunk within 128B row
    const unsigned boff = sub * 16u;

    float acc[16];
#pragma unroll
    for (int k = 0; k < 16; ++k) acc[k] = 0.f;

    for (int base = start; base < end; base += 64) {
        const int  idx   = base + lane;
        const bool valid = idx < end;
        const int   c  = __builtin_nontemporal_load(&cols[valid ? idx : start]);
        const float wf = valid ? __builtin_nontemporal_load(&wfold[idx]) : 0.f;
        const int seg = end - base;                // wave-uniform

        int   ct[8];
        float wt[8];
        uint4 g[8];

        // Phase A: redistribute cols+folded weights (8-nnz granules)
#pragma unroll
        for (int t8 = 0; t8 < 8; ++t8) {
            if (t8 * 8 < seg) {
                const int pa = (t8 * 8 + slot) * 4;
                ct[t8] = __builtin_amdgcn_ds_bpermute(pa, c);
                wt[t8] = __uint_as_float(__builtin_amdgcn_ds_bpermute(
                    pa, __float_as_uint(wf)));
            }
        }
        // Phase B: issue all gathers (8 dwordx4 in flight, 8 nnz each)
#pragma unroll
        for (int t8 = 0; t8 < 8; ++t8) {
            if (t8 * 8 < seg)
                g[t8] = *(const uint4*)(ex8 +
                        ((size_t)(unsigned)ct[t8] << 7) + boff);
        }
        // Phase C: consume (fp8 -> f32 via packed HW cvt)
#pragma unroll
        for (int t8 = 0; t8 < 8; ++t8) {
            if (t8 * 8 < seg) {
                const float wtv = wt[t8];
                const unsigned* gu = (const unsigned*)&g[t8];
#pragma unroll
                for (int q = 0; q < 4; ++q) {
                    const fx2 lo = __builtin_amdgcn_cvt_pk_f32_fp8((int)gu[q], false);
                    const fx2 hi = __builtin_amdgcn_cvt_pk_f32_fp8((int)gu[q], true);
                    acc[q * 4 + 0] = fmaf(wtv, lo.x, acc[q * 4 + 0]);
                    acc[q * 4 + 1] = fmaf(wtv, lo.y, acc[q * 4 + 1]);
                    acc[q * 4 + 2] = fmaf(wtv, hi.x, acc[q * 4 + 2]);
                    acc[q * 4 + 3] = fmaf(wtv, hi.y, acc[q * 4 + 3]);
                }
            }
        }
    }

    // fold the 8 slot-groups (same batch samples) together
#pragma unroll
    for (int k = 0; k < 16; ++k) {
        acc[k] += __shfl_xor(acc[k], 8, 64);
        acc[k] += __shfl_xor(acc[k], 16, 64);
        acc[k] += __shfl_xor(acc[k], 32, 64);
    }

    if (lane < 8) {
        const int b0 = lane * 16;
#pragma unroll
        for (int k = 0; k < 16; ++k)
            out[(size_t)(b0 + k) * N_NODES + r] = logf(acc[k]) - lz;
    }
}

// ---------------------------------------------------------------------------
extern "C" void kernel_launch(void* const* d_in, const int* in_sizes, int n_in,
                              void* d_out, int out_size, void* d_ws, size_t ws_size,
                              hipStream_t stream) {
    const float* child_ll = (const float*)d_in[0];
    const float* log_w    = (const float*)d_in[1];
    const int*   rows     = (const int*)d_in[2];
    const int*   cols     = (const int*)d_in[3];
    float*       out      = (float*)d_out;

    unsigned char* ex8 = (unsigned char*)d_ws;                             // 8.4 MB
    float* winv      = (float*)((char*)d_ws + (size_t)N_CHILD * 128);      // 256 KB
    float* wfold     = (float*)((char*)winv + (size_t)N_CHILD * 4);        // 4 MB
    int*   row_start = (int*)((char*)wfold + (size_t)NNZ_TOTAL * 4);       // 128 KB
    float* logzv     = (float*)((char*)row_start + (size_t)(N_NODES + 1) * 4);

    exp8_kernel<<<N_CHILD / 64, 256, 0, stream>>>(child_ll, ex8, winv);
    fold_scan_kernel<<<NNZ_TOTAL / 1024, 256, 0, stream>>>(
        log_w, cols, winv, rows, wfold, row_start);
    logz_kernel<<<N_NODES / 16, 256, 0, stream>>>(log_w, row_start, logzv);
    sum_rows_kernel<<<N_NODES / 4, 256, 0, stream>>>(ex8, wfold, cols,
                                                     row_start, logzv, out);
}

// Round 13
// 68.605 us; speedup vs baseline: 2.8819x; 2.8819x over previous
//
#include <hip/hip_runtime.h>
#include <math.h>

#define BATCH     128
#define N_NODES   32768
#define N_CHILD   65536
#define NNZ_TOTAL 1048576
#define LOG2E     1.44269504f

typedef __attribute__((ext_vector_type(2))) float fx2;

// ---------------------------------------------------------------------------
// Kernel A: fp8 exp table, per-column power-of-2 scale, register-resident.
// Also zeroes zsum (consumed by fold_scan's atomics next in stream order).
// ---------------------------------------------------------------------------
__global__ __launch_bounds__(256) void exp8_kernel(
    const float* __restrict__ child_ll, unsigned char* __restrict__ ex8,
    float* __restrict__ winv, float* __restrict__ zsum) {
    const int c0 = blockIdx.x * 64;
    const int t  = threadIdx.x;
    const int gid = blockIdx.x * 256 + t;
    if (gid < N_NODES) zsum[gid] = 0.f;

    const int cl = t & 63;
    const int q  = t >> 6;                 // batch quarter [q*32, q*32+32)

    float v[32];
    float m = -3.4e38f;
    const float* bp = child_ll + (size_t)(q * 32) * N_CHILD + c0 + cl;
#pragma unroll
    for (int j = 0; j < 32; ++j) {
        v[j] = bp[(size_t)j * N_CHILD];
        m = fmaxf(m, v[j]);
    }

    __shared__ float smx[4][64];
    __shared__ float skf[64];
    smx[q][cl] = m;
    __syncthreads();
    if (t < 64) {
        const float mm = fmaxf(fmaxf(smx[0][t], smx[1][t]),
                               fmaxf(smx[2][t], smx[3][t]));
        const int ks = 7 - (int)floorf(mm * LOG2E);   // colmax*2^ks in [128,256)
        skf[t] = (float)ks;
        winv[c0 + t] = exp2f((float)(-ks));
    }
    __syncthreads();
    const float kf = skf[cl];

    unsigned ow[8];
#pragma unroll
    for (int p = 0; p < 8; ++p) {
        const float a0 = exp2f(fmaf(v[4 * p + 0], LOG2E, kf));
        const float a1 = exp2f(fmaf(v[4 * p + 1], LOG2E, kf));
        const float a2 = exp2f(fmaf(v[4 * p + 2], LOG2E, kf));
        const float a3 = exp2f(fmaf(v[4 * p + 3], LOG2E, kf));
        unsigned u = 0;
        u = __builtin_amdgcn_cvt_pk_fp8_f32(a0, a1, u, false);
        u = __builtin_amdgcn_cvt_pk_fp8_f32(a2, a3, u, true);
        ow[p] = u;
    }

    __shared__ unsigned char sby[64 * 144];
    *(uint4*)&sby[cl * 144 + q * 32]      = *(uint4*)&ow[0];
    *(uint4*)&sby[cl * 144 + q * 32 + 16] = *(uint4*)&ow[4];
    __syncthreads();

    const int sub = t & 7, cc = t >> 3;
#pragma unroll
    for (int p = 0; p < 2; ++p) {
        const int c = cc + p * 32;
        *(uint4*)&ex8[(size_t)(c0 + c) * 128 + sub * 16] =
            *(const uint4*)&sby[c * 144 + sub * 16];
    }
}

// ---------------------------------------------------------------------------
// Kernel B: wfold[i] = exp(log_w[i]) * winv[cols[i]]  +  row_start via
// sorted-COO scan  +  zsum[r] += exp(log_w) (segmented, 1-4 atomics/thread).
// ---------------------------------------------------------------------------
__global__ __launch_bounds__(256) void fold_scan_kernel(
    const float* __restrict__ log_w, const int* __restrict__ cols,
    const float* __restrict__ winv, const int* __restrict__ rows,
    float* __restrict__ wfold, int* __restrict__ row_start,
    float* __restrict__ zsum) {
    const int i = (blockIdx.x * 256 + threadIdx.x) * 4;
    const float4 lw = *(const float4*)&log_w[i];
    const int4   cc = *(const int4*)&cols[i];
    const float ew0 = expf(lw.x), ew1 = expf(lw.y);
    const float ew2 = expf(lw.z), ew3 = expf(lw.w);
    float4 o;
    o.x = ew0 * winv[cc.x];
    o.y = ew1 * winv[cc.y];
    o.z = ew2 * winv[cc.z];
    o.w = ew3 * winv[cc.w];
    *(float4*)&wfold[i] = o;

    const int4 rv = *(const int4*)&rows[i];
    const int rj[4] = {rv.x, rv.y, rv.z, rv.w};
    const float ej[4] = {ew0, ew1, ew2, ew3};

    // segmented zsum accumulation (rows sorted => runs are contiguous)
    float s = ej[0];
#pragma unroll
    for (int j = 1; j < 4; ++j) {
        if (rj[j] == rj[j - 1]) s += ej[j];
        else { atomicAdd(&zsum[rj[j - 1]], s); s = ej[j]; }
    }
    atomicAdd(&zsum[rj[3]], s);

    // row_start scan
    int prev = (i == 0) ? -1 : rows[i - 1];
#pragma unroll
    for (int j = 0; j < 4; ++j) {
        const int cur = rj[j];
        if (cur != prev)
            for (int q = prev + 1; q <= cur; ++q) row_start[q] = i + j;
        prev = cur;
    }
    if (i + 3 == NNZ_TOTAL - 1)
        for (int q = rj[3] + 1; q <= N_NODES; ++q) row_start[q] = NNZ_TOTAL;
}

// ---------------------------------------------------------------------------
// Kernel C: per-row sum, one wave per row (R11 schedule, launch_bounds
// reverted to (256,4)). Epilogue spread: all 64 lanes, 2 logf + 2 stores
// each (was 16 logf + 16 stores on 8 lanes).
// ---------------------------------------------------------------------------
__global__ __launch_bounds__(256, 4) void sum_rows_kernel(
    const unsigned char* __restrict__ ex8, const float* __restrict__ wfold,
    const int* __restrict__ cols, const int* __restrict__ row_start,
    const float* __restrict__ zsum, float* __restrict__ out) {
    const int wave = threadIdx.x >> 6;   // 0..3
    const int lane = threadIdx.x & 63;
    const int bid  = blockIdx.x;         // grid = 8192
    const int rb   = (bid & 7) * (N_NODES / 4 / 8) + (bid >> 3);
    const int r    = rb * 4 + wave;

    const int start = row_start[r];
    const int end   = row_start[r + 1];
    const float zs  = zsum[r];                     // issued early, used last
    const int  slot = lane >> 3;                   // nnz slot within granule
    const unsigned sub = (unsigned)lane & 7u;      // 16B chunk within 128B row
    const unsigned boff = sub * 16u;

    float acc[16];
#pragma unroll
    for (int k = 0; k < 16; ++k) acc[k] = 0.f;

    for (int base = start; base < end; base += 64) {
        const int  idx   = base + lane;
        const bool valid = idx < end;
        const int   c  = __builtin_nontemporal_load(&cols[valid ? idx : start]);
        const float wf = valid ? __builtin_nontemporal_load(&wfold[idx]) : 0.f;
        const int seg = end - base;                // wave-uniform

        int   ct[8];
        float wt[8];
        uint4 g[8];

        // Phase A: redistribute cols+folded weights (8-nnz granules)
#pragma unroll
        for (int t8 = 0; t8 < 8; ++t8) {
            if (t8 * 8 < seg) {
                const int pa = (t8 * 8 + slot) * 4;
                ct[t8] = __builtin_amdgcn_ds_bpermute(pa, c);
                wt[t8] = __uint_as_float(__builtin_amdgcn_ds_bpermute(
                    pa, __float_as_uint(wf)));
            }
        }
        // Phase B: issue all gathers (8 dwordx4 in flight, 8 nnz each)
#pragma unroll
        for (int t8 = 0; t8 < 8; ++t8) {
            if (t8 * 8 < seg)
                g[t8] = *(const uint4*)(ex8 +
                        ((size_t)(unsigned)ct[t8] << 7) + boff);
        }
        // Phase C: consume (fp8 -> f32 via packed HW cvt)
#pragma unroll
        for (int t8 = 0; t8 < 8; ++t8) {
            if (t8 * 8 < seg) {
                const float wtv = wt[t8];
                const unsigned* gu = (const unsigned*)&g[t8];
#pragma unroll
                for (int q = 0; q < 4; ++q) {
                    const fx2 lo = __builtin_amdgcn_cvt_pk_f32_fp8((int)gu[q], false);
                    const fx2 hi = __builtin_amdgcn_cvt_pk_f32_fp8((int)gu[q], true);
                    acc[q * 4 + 0] = fmaf(wtv, lo.x, acc[q * 4 + 0]);
                    acc[q * 4 + 1] = fmaf(wtv, lo.y, acc[q * 4 + 1]);
                    acc[q * 4 + 2] = fmaf(wtv, hi.x, acc[q * 4 + 2]);
                    acc[q * 4 + 3] = fmaf(wtv, hi.y, acc[q * 4 + 3]);
                }
            }
        }
    }

    // fold the 8 slot-groups: every lane ends with all 16 totals for its sub
#pragma unroll
    for (int k = 0; k < 16; ++k) {
        acc[k] += __shfl_xor(acc[k], 8, 64);
        acc[k] += __shfl_xor(acc[k], 16, 64);
        acc[k] += __shfl_xor(acc[k], 32, 64);
    }

    // spread epilogue: lane (sub, p=lane>>3) writes batch pair k = 2p, 2p+1
    const float lz = logf(zs);
    const int p  = lane >> 3;
    const int b0 = (int)sub * 16 + 2 * p;
    float v0 = acc[0], v1 = acc[1];
#pragma unroll
    for (int kk = 1; kk < 8; ++kk) {
        v0 = (p == kk) ? acc[2 * kk]     : v0;
        v1 = (p == kk) ? acc[2 * kk + 1] : v1;
    }
    out[(size_t)b0 * N_NODES + r]       = logf(v0) - lz;
    out[(size_t)(b0 + 1) * N_NODES + r] = logf(v1) - lz;
}

// ---------------------------------------------------------------------------
extern "C" void kernel_launch(void* const* d_in, const int* in_sizes, int n_in,
                              void* d_out, int out_size, void* d_ws, size_t ws_size,
                              hipStream_t stream) {
    const float* child_ll = (const float*)d_in[0];
    const float* log_w    = (const float*)d_in[1];
    const int*   rows     = (const int*)d_in[2];
    const int*   cols     = (const int*)d_in[3];
    float*       out      = (float*)d_out;

    unsigned char* ex8 = (unsigned char*)d_ws;                             // 8.4 MB
    float* winv      = (float*)((char*)d_ws + (size_t)N_CHILD * 128);      // 256 KB
    float* wfold     = (float*)((char*)winv + (size_t)N_CHILD * 4);        // 4 MB
    int*   row_start = (int*)((char*)wfold + (size_t)NNZ_TOTAL * 4);       // 128 KB
    float* zsum      = (float*)((char*)row_start + (size_t)(N_NODES + 1) * 4);

    exp8_kernel<<<N_CHILD / 64, 256, 0, stream>>>(child_ll, ex8, winv, zsum);
    fold_scan_kernel<<<NNZ_TOTAL / 1024, 256, 0, stream>>>(
        log_w, cols, winv, rows, wfold, row_start, zsum);
    sum_rows_kernel<<<N_NODES / 4, 256, 0, stream>>>(ex8, wfold, cols,
                                                     row_start, zsum, out);
}

// Round 14
// 67.885 us; speedup vs baseline: 2.9125x; 1.0106x over previous
//
#include <hip/hip_runtime.h>
#include <math.h>

#define BATCH     128
#define N_NODES   32768
#define N_CHILD   65536
#define NNZ_TOTAL 1048576
#define LOG2E     1.44269504f

typedef __attribute__((ext_vector_type(2))) float fx2;

// ---------------------------------------------------------------------------
// Kernel A: fp8 exp table, per-column power-of-2 scale, register-resident.
// ---------------------------------------------------------------------------
__global__ __launch_bounds__(256) void exp8_kernel(
    const float* __restrict__ child_ll, unsigned char* __restrict__ ex8,
    float* __restrict__ winv) {
    const int c0 = blockIdx.x * 64;
    const int t  = threadIdx.x;
    const int cl = t & 63;
    const int q  = t >> 6;                 // batch quarter [q*32, q*32+32)

    float v[32];
    float m = -3.4e38f;
    const float* bp = child_ll + (size_t)(q * 32) * N_CHILD + c0 + cl;
#pragma unroll
    for (int j = 0; j < 32; ++j) {
        v[j] = bp[(size_t)j * N_CHILD];
        m = fmaxf(m, v[j]);
    }

    __shared__ float smx[4][64];
    __shared__ float skf[64];
    smx[q][cl] = m;
    __syncthreads();
    if (t < 64) {
        const float mm = fmaxf(fmaxf(smx[0][t], smx[1][t]),
                               fmaxf(smx[2][t], smx[3][t]));
        const int ks = 7 - (int)floorf(mm * LOG2E);   // colmax*2^ks in [128,256)
        skf[t] = (float)ks;
        winv[c0 + t] = exp2f((float)(-ks));
    }
    __syncthreads();
    const float kf = skf[cl];

    unsigned ow[8];
#pragma unroll
    for (int p = 0; p < 8; ++p) {
        const float a0 = exp2f(fmaf(v[4 * p + 0], LOG2E, kf));
        const float a1 = exp2f(fmaf(v[4 * p + 1], LOG2E, kf));
        const float a2 = exp2f(fmaf(v[4 * p + 2], LOG2E, kf));
        const float a3 = exp2f(fmaf(v[4 * p + 3], LOG2E, kf));
        unsigned u = 0;
        u = __builtin_amdgcn_cvt_pk_fp8_f32(a0, a1, u, false);
        u = __builtin_amdgcn_cvt_pk_fp8_f32(a2, a3, u, true);
        ow[p] = u;
    }

    __shared__ unsigned char sby[64 * 144];
    *(uint4*)&sby[cl * 144 + q * 32]      = *(uint4*)&ow[0];
    *(uint4*)&sby[cl * 144 + q * 32 + 16] = *(uint4*)&ow[4];
    __syncthreads();

    const int sub = t & 7, cc = t >> 3;
#pragma unroll
    for (int p = 0; p < 2; ++p) {
        const int c = cc + p * 32;
        *(uint4*)&ex8[(size_t)(c0 + c) * 128 + sub * 16] =
            *(const uint4*)&sby[c * 144 + sub * 16];
    }
}

// ---------------------------------------------------------------------------
// Kernel B (merged prep, race-free):
//  blocks [0,1024):   wfold[i] = exp(log_w[i]) * winv[cols[i]]  +  row_start
//                     via sorted-COO scan (4 nnz/thread, coalesced).
//  blocks [1024,3072): logzv for 16 rows/block — block binary-searches its
//                     own segment bounds from rows directly (independent of
//                     row_start), segmented LDS-atomic reduce over 16 slots.
// ---------------------------------------------------------------------------
__global__ __launch_bounds__(256) void prep_kernel(
    const float* __restrict__ log_w, const int* __restrict__ cols,
    const float* __restrict__ winv, const int* __restrict__ rows,
    float* __restrict__ wfold, int* __restrict__ row_start,
    float* __restrict__ logzv) {
    const int bid = blockIdx.x;
    const int t   = threadIdx.x;

    if (bid < 1024) {
        const int i = (bid * 256 + t) * 4;
        const float4 lw = *(const float4*)&log_w[i];
        const int4   cc = *(const int4*)&cols[i];
        float4 o;
        o.x = expf(lw.x) * winv[cc.x];
        o.y = expf(lw.y) * winv[cc.y];
        o.z = expf(lw.z) * winv[cc.z];
        o.w = expf(lw.w) * winv[cc.w];
        *(float4*)&wfold[i] = o;

        const int4 rv = *(const int4*)&rows[i];
        const int rj[4] = {rv.x, rv.y, rv.z, rv.w};
        int prev = (i == 0) ? -1 : rows[i - 1];
#pragma unroll
        for (int j = 0; j < 4; ++j) {
            const int cur = rj[j];
            if (cur != prev)
                for (int q = prev + 1; q <= cur; ++q) row_start[q] = i + j;
            prev = cur;
        }
        if (i + 3 == NNZ_TOTAL - 1)
            for (int q = rj[3] + 1; q <= N_NODES; ++q) row_start[q] = NNZ_TOTAL;
    } else {
        const int r0 = (bid - 1024) * 16;
        // wave-uniform binary searches for [start(r0), start(r0+16))
        int lo = 0, hi = NNZ_TOTAL;
        while (lo < hi) {
            const int mid = (lo + hi) >> 1;
            if (rows[mid] < r0) lo = mid + 1; else hi = mid;
        }
        const int s0 = lo;
        int lo2 = s0, hi2 = NNZ_TOTAL;
        while (lo2 < hi2) {
            const int mid = (lo2 + hi2) >> 1;
            if (rows[mid] < r0 + 16) lo2 = mid + 1; else hi2 = mid;
        }
        const int e0 = lo2;

        __shared__ float slot[16];
        if (t < 16) slot[t] = 0.f;
        __syncthreads();
        for (int i = s0 + t; i < e0; i += 256)
            atomicAdd(&slot[rows[i] - r0], expf(log_w[i]));
        __syncthreads();
        if (t < 16) logzv[r0 + t] = logf(slot[t]);
    }
}

// ---------------------------------------------------------------------------
// Kernel C: per-row sum, one wave per row (R11 schedule + R13 spread
// epilogue: all 64 lanes, 2 logf + 2 stores each).
// ---------------------------------------------------------------------------
__global__ __launch_bounds__(256, 4) void sum_rows_kernel(
    const unsigned char* __restrict__ ex8, const float* __restrict__ wfold,
    const int* __restrict__ cols, const int* __restrict__ row_start,
    const float* __restrict__ logzv, float* __restrict__ out) {
    const int wave = threadIdx.x >> 6;   // 0..3
    const int lane = threadIdx.x & 63;
    const int bid  = blockIdx.x;         // grid = 8192
    const int rb   = (bid & 7) * (N_NODES / 4 / 8) + (bid >> 3);
    const int r    = rb * 4 + wave;

    const int start = row_start[r];
    const int end   = row_start[r + 1];
    const float lz  = logzv[r];                    // issued early, used last
    const int  slot = lane >> 3;                   // nnz slot within granule
    const unsigned sub = (unsigned)lane & 7u;      // 16B chunk within 128B row
    const unsigned boff = sub * 16u;

    float acc[16];
#pragma unroll
    for (int k = 0; k < 16; ++k) acc[k] = 0.f;

    for (int base = start; base < end; base += 64) {
        const int  idx   = base + lane;
        const bool valid = idx < end;
        const int   c  = __builtin_nontemporal_load(&cols[valid ? idx : start]);
        const float wf = valid ? __builtin_nontemporal_load(&wfold[idx]) : 0.f;
        const int seg = end - base;                // wave-uniform

        int   ct[8];
        float wt[8];
        uint4 g[8];

        // Phase A: redistribute cols+folded weights (8-nnz granules)
#pragma unroll
        for (int t8 = 0; t8 < 8; ++t8) {
            if (t8 * 8 < seg) {
                const int pa = (t8 * 8 + slot) * 4;
                ct[t8] = __builtin_amdgcn_ds_bpermute(pa, c);
                wt[t8] = __uint_as_float(__builtin_amdgcn_ds_bpermute(
                    pa, __float_as_uint(wf)));
            }
        }
        // Phase B: issue all gathers (8 dwordx4 in flight, 8 nnz each)
#pragma unroll
        for (int t8 = 0; t8 < 8; ++t8) {
            if (t8 * 8 < seg)
                g[t8] = *(const uint4*)(ex8 +
                        ((size_t)(unsigned)ct[t8] << 7) + boff);
        }
        // Phase C: consume (fp8 -> f32 via packed HW cvt)
#pragma unroll
        for (int t8 = 0; t8 < 8; ++t8) {
            if (t8 * 8 < seg) {
                const float wtv = wt[t8];
                const unsigned* gu = (const unsigned*)&g[t8];
#pragma unroll
                for (int q = 0; q < 4; ++q) {
                    const fx2 lo = __builtin_amdgcn_cvt_pk_f32_fp8((int)gu[q], false);
                    const fx2 hi = __builtin_amdgcn_cvt_pk_f32_fp8((int)gu[q], true);
                    acc[q * 4 + 0] = fmaf(wtv, lo.x, acc[q * 4 + 0]);
                    acc[q * 4 + 1] = fmaf(wtv, lo.y, acc[q * 4 + 1]);
                    acc[q * 4 + 2] = fmaf(wtv, hi.x, acc[q * 4 + 2]);
                    acc[q * 4 + 3] = fmaf(wtv, hi.y, acc[q * 4 + 3]);
                }
            }
        }
    }

    // fold the 8 slot-groups: every lane ends with all 16 totals for its sub
#pragma unroll
    for (int k = 0; k < 16; ++k) {
        acc[k] += __shfl_xor(acc[k], 8, 64);
        acc[k] += __shfl_xor(acc[k], 16, 64);
        acc[k] += __shfl_xor(acc[k], 32, 64);
    }

    // spread epilogue: lane (sub, p=lane>>3) writes batch pair k = 2p, 2p+1
    const int p  = lane >> 3;
    const int b0 = (int)sub * 16 + 2 * p;
    float v0 = acc[0], v1 = acc[1];
#pragma unroll
    for (int kk = 1; kk < 8; ++kk) {
        v0 = (p == kk) ? acc[2 * kk]     : v0;
        v1 = (p == kk) ? acc[2 * kk + 1] : v1;
    }
    out[(size_t)b0 * N_NODES + r]       = logf(v0) - lz;
    out[(size_t)(b0 + 1) * N_NODES + r] = logf(v1) - lz;
}

// ---------------------------------------------------------------------------
extern "C" void kernel_launch(void* const* d_in, const int* in_sizes, int n_in,
                              void* d_out, int out_size, void* d_ws, size_t ws_size,
                              hipStream_t stream) {
    const float* child_ll = (const float*)d_in[0];
    const float* log_w    = (const float*)d_in[1];
    const int*   rows     = (const int*)d_in[2];
    const int*   cols     = (const int*)d_in[3];
    float*       out      = (float*)d_out;

    unsigned char* ex8 = (unsigned char*)d_ws;                             // 8.4 MB
    float* winv      = (float*)((char*)d_ws + (size_t)N_CHILD * 128);      // 256 KB
    float* wfold     = (float*)((char*)winv + (size_t)N_CHILD * 4);        // 4 MB
    int*   row_start = (int*)((char*)wfold + (size_t)NNZ_TOTAL * 4);       // 128 KB
    float* logzv     = (float*)((char*)row_start + (size_t)(N_NODES + 1) * 4);

    exp8_kernel<<<N_CHILD / 64, 256, 0, stream>>>(child_ll, ex8, winv);
    prep_kernel<<<3072, 256, 0, stream>>>(log_w, cols, winv, rows,
                                          wfold, row_start, logzv);
    sum_rows_kernel<<<N_NODES / 4, 256, 0, stream>>>(ex8, wfold, cols,
                                                     row_start, logzv, out);
}

// Round 15
// 60.019 us; speedup vs baseline: 3.2942x; 1.1311x over previous
//
#include <hip/hip_runtime.h>
#include <math.h>

#define BATCH     128
#define N_NODES   32768
#define N_CHILD   65536
#define NNZ_TOTAL 1048576
#define LOG2E     1.44269504f

typedef __attribute__((ext_vector_type(2))) float fx2;

// ---------------------------------------------------------------------------
// Kernel A: fp8 exp table, per-column power-of-2 scale, register-resident.
// ---------------------------------------------------------------------------
__global__ __launch_bounds__(256) void exp8_kernel(
    const float* __restrict__ child_ll, unsigned char* __restrict__ ex8,
    float* __restrict__ winv) {
    const int c0 = blockIdx.x * 64;
    const int t  = threadIdx.x;
    const int cl = t & 63;
    const int q  = t >> 6;                 // batch quarter [q*32, q*32+32)

    float v[32];
    float m = -3.4e38f;
    const float* bp = child_ll + (size_t)(q * 32) * N_CHILD + c0 + cl;
#pragma unroll
    for (int j = 0; j < 32; ++j) {
        v[j] = bp[(size_t)j * N_CHILD];
        m = fmaxf(m, v[j]);
    }

    __shared__ float smx[4][64];
    __shared__ float skf[64];
    smx[q][cl] = m;
    __syncthreads();
    if (t < 64) {
        const float mm = fmaxf(fmaxf(smx[0][t], smx[1][t]),
                               fmaxf(smx[2][t], smx[3][t]));
        const int ks = 7 - (int)floorf(mm * LOG2E);   // colmax*2^ks in [128,256)
        skf[t] = (float)ks;
        winv[c0 + t] = exp2f((float)(-ks));
    }
    __syncthreads();
    const float kf = skf[cl];

    unsigned ow[8];
#pragma unroll
    for (int p = 0; p < 8; ++p) {
        const float a0 = exp2f(fmaf(v[4 * p + 0], LOG2E, kf));
        const float a1 = exp2f(fmaf(v[4 * p + 1], LOG2E, kf));
        const float a2 = exp2f(fmaf(v[4 * p + 2], LOG2E, kf));
        const float a3 = exp2f(fmaf(v[4 * p + 3], LOG2E, kf));
        unsigned u = 0;
        u = __builtin_amdgcn_cvt_pk_fp8_f32(a0, a1, u, false);
        u = __builtin_amdgcn_cvt_pk_fp8_f32(a2, a3, u, true);
        ow[p] = u;
    }

    __shared__ unsigned char sby[64 * 144];
    *(uint4*)&sby[cl * 144 + q * 32]      = *(uint4*)&ow[0];
    *(uint4*)&sby[cl * 144 + q * 32 + 16] = *(uint4*)&ow[4];
    __syncthreads();

    const int sub = t & 7, cc = t >> 3;
#pragma unroll
    for (int p = 0; p < 2; ++p) {
        const int c = cc + p * 32;
        *(uint4*)&ex8[(size_t)(c0 + c) * 128 + sub * 16] =
            *(const uint4*)&sby[c * 144 + sub * 16];
    }
}

// ---------------------------------------------------------------------------
// Kernel B: wfold[i] = exp(log_w[i]) * winv[cols[i]]  +  row_start via
// sorted-COO scan (no binary search). 4 nnz per thread, fully coalesced.
// ---------------------------------------------------------------------------
__global__ __launch_bounds__(256) void fold_scan_kernel(
    const float* __restrict__ log_w, const int* __restrict__ cols,
    const float* __restrict__ winv, const int* __restrict__ rows,
    float* __restrict__ wfold, int* __restrict__ row_start) {
    const int i = (blockIdx.x * 256 + threadIdx.x) * 4;
    const float4 lw = *(const float4*)&log_w[i];
    const int4   cc = *(const int4*)&cols[i];
    float4 o;
    o.x = expf(lw.x) * winv[cc.x];
    o.y = expf(lw.y) * winv[cc.y];
    o.z = expf(lw.z) * winv[cc.z];
    o.w = expf(lw.w) * winv[cc.w];
    *(float4*)&wfold[i] = o;

    const int4 rv = *(const int4*)&rows[i];
    const int rj[4] = {rv.x, rv.y, rv.z, rv.w};
    int prev = (i == 0) ? -1 : rows[i - 1];
#pragma unroll
    for (int j = 0; j < 4; ++j) {
        const int cur = rj[j];
        if (cur != prev)
            for (int q = prev + 1; q <= cur; ++q) row_start[q] = i + j;
        prev = cur;
    }
    if (i + 3 == NNZ_TOTAL - 1)
        for (int q = rj[3] + 1; q <= N_NODES; ++q) row_start[q] = NNZ_TOTAL;
}

// ---------------------------------------------------------------------------
// Kernel C: logzv[r] = log(sum exp(log_w[row segment])). 16 lanes/row,
// contiguous coalesced segment reads.
// ---------------------------------------------------------------------------
__global__ __launch_bounds__(256) void logz_kernel(
    const float* __restrict__ log_w, const int* __restrict__ row_start,
    float* __restrict__ logzv) {
    const int t = threadIdx.x;
    const int g = t >> 4, j = t & 15;
    const int r = blockIdx.x * 16 + g;
    const int s = row_start[r], e = row_start[r + 1];
    float sum = 0.f;
    for (int i = s + j; i < e; i += 16) sum += expf(log_w[i]);
    sum += __shfl_xor(sum, 1, 64);
    sum += __shfl_xor(sum, 2, 64);
    sum += __shfl_xor(sum, 4, 64);
    sum += __shfl_xor(sum, 8, 64);
    if (j == 0) logzv[r] = logf(sum);
}

// ---------------------------------------------------------------------------
// Kernel D: per-row sum, one wave per row (best-measured schedule: 64-nnz
// tile, bpermute meta redistribution, 8 dwordx4 gathers in flight, shfl
// fold, spread epilogue: all 64 lanes write 2 values each).
// ---------------------------------------------------------------------------
__global__ __launch_bounds__(256, 4) void sum_rows_kernel(
    const unsigned char* __restrict__ ex8, const float* __restrict__ wfold,
    const int* __restrict__ cols, const int* __restrict__ row_start,
    const float* __restrict__ logzv, float* __restrict__ out) {
    const int wave = threadIdx.x >> 6;   // 0..3
    const int lane = threadIdx.x & 63;
    const int bid  = blockIdx.x;         // grid = 8192
    const int rb   = (bid & 7) * (N_NODES / 4 / 8) + (bid >> 3);
    const int r    = rb * 4 + wave;

    const int start = row_start[r];
    const int end   = row_start[r + 1];
    const float lz  = logzv[r];                    // issued early, used last
    const int  slot = lane >> 3;                   // nnz slot within granule
    const unsigned sub = (unsigned)lane & 7u;      // 16B chunk within 128B row
    const unsigned boff = sub * 16u;

    float acc[16];
#pragma unroll
    for (int k = 0; k < 16; ++k) acc[k] = 0.f;

    for (int base = start; base < end; base += 64) {
        const int  idx   = base + lane;
        const bool valid = idx < end;
        const int   c  = __builtin_nontemporal_load(&cols[valid ? idx : start]);
        const float wf = valid ? __builtin_nontemporal_load(&wfold[idx]) : 0.f;
        const int seg = end - base;                // wave-uniform

        int   ct[8];
        float wt[8];
        uint4 g[8];

        // Phase A: redistribute cols+folded weights (8-nnz granules)
#pragma unroll
        for (int t8 = 0; t8 < 8; ++t8) {
            if (t8 * 8 < seg) {
                const int pa = (t8 * 8 + slot) * 4;
                ct[t8] = __builtin_amdgcn_ds_bpermute(pa, c);
                wt[t8] = __uint_as_float(__builtin_amdgcn_ds_bpermute(
                    pa, __float_as_uint(wf)));
            }
        }
        // Phase B: issue all gathers (8 dwordx4 in flight, 8 nnz each)
#pragma unroll
        for (int t8 = 0; t8 < 8; ++t8) {
            if (t8 * 8 < seg)
                g[t8] = *(const uint4*)(ex8 +
                        ((size_t)(unsigned)ct[t8] << 7) + boff);
        }
        // Phase C: consume (fp8 -> f32 via packed HW cvt)
#pragma unroll
        for (int t8 = 0; t8 < 8; ++t8) {
            if (t8 * 8 < seg) {
                const float wtv = wt[t8];
                const unsigned* gu = (const unsigned*)&g[t8];
#pragma unroll
                for (int q = 0; q < 4; ++q) {
                    const fx2 lo = __builtin_amdgcn_cvt_pk_f32_fp8((int)gu[q], false);
                    const fx2 hi = __builtin_amdgcn_cvt_pk_f32_fp8((int)gu[q], true);
                    acc[q * 4 + 0] = fmaf(wtv, lo.x, acc[q * 4 + 0]);
                    acc[q * 4 + 1] = fmaf(wtv, lo.y, acc[q * 4 + 1]);
                    acc[q * 4 + 2] = fmaf(wtv, hi.x, acc[q * 4 + 2]);
                    acc[q * 4 + 3] = fmaf(wtv, hi.y, acc[q * 4 + 3]);
                }
            }
        }
    }

    // fold the 8 slot-groups: every lane ends with all 16 totals for its sub
#pragma unroll
    for (int k = 0; k < 16; ++k) {
        acc[k] += __shfl_xor(acc[k], 8, 64);
        acc[k] += __shfl_xor(acc[k], 16, 64);
        acc[k] += __shfl_xor(acc[k], 32, 64);
    }

    // spread epilogue: lane (sub, p=lane>>3) writes batch pair k = 2p, 2p+1
    const int p  = lane >> 3;
    const int b0 = (int)sub * 16 + 2 * p;
    float v0 = acc[0], v1 = acc[1];
#pragma unroll
    for (int kk = 1; kk < 8; ++kk) {
        v0 = (p == kk) ? acc[2 * kk]     : v0;
        v1 = (p == kk) ? acc[2 * kk + 1] : v1;
    }
    out[(size_t)b0 * N_NODES + r]       = logf(v0) - lz;
    out[(size_t)(b0 + 1) * N_NODES + r] = logf(v1) - lz;
}

// ---------------------------------------------------------------------------
extern "C" void kernel_launch(void* const* d_in, const int* in_sizes, int n_in,
                              void* d_out, int out_size, void* d_ws, size_t ws_size,
                              hipStream_t stream) {
    const float* child_ll = (const float*)d_in[0];
    const float* log_w    = (const float*)d_in[1];
    const int*   rows     = (const int*)d_in[2];
    const int*   cols     = (const int*)d_in[3];
    float*       out      = (float*)d_out;

    unsigned char* ex8 = (unsigned char*)d_ws;                             // 8.4 MB
    float* winv      = (float*)((char*)d_ws + (size_t)N_CHILD * 128);      // 256 KB
    float* wfold     = (float*)((char*)winv + (size_t)N_CHILD * 4);        // 4 MB
    int*   row_start = (int*)((char*)wfold + (size_t)NNZ_TOTAL * 4);       // 128 KB
    float* logzv     = (float*)((char*)row_start + (size_t)(N_NODES + 1) * 4);

    exp8_kernel<<<N_CHILD / 64, 256, 0, stream>>>(child_ll, ex8, winv);
    fold_scan_kernel<<<NNZ_TOTAL / 1024, 256, 0, stream>>>(
        log_w, cols, winv, rows, wfold, row_start);
    logz_kernel<<<N_NODES / 16, 256, 0, stream>>>(log_w, row_start, logzv);
    sum_rows_kernel<<<N_NODES / 4, 256, 0, stream>>>(ex8, wfold, cols,
                                                     row_start, logzv, out);
}